// Round 1
// baseline (706.754 us; speedup 1.0000x reference)
//
#include <hip/hip_runtime.h>
#include <hip/hip_bf16.h>
#include <cstdint>
#include <cstddef>

// Problem constants (Qwen2: B=2,S=4096,H=3584,NH=28,NKV=4,D=128)
#define SS 4096
#define HH 3584
#define NHQ 28
#define NKVH 4
#define DD 128
#define MM 8192                 // B*S
#define NN 4608                 // (NH+2*NKV)*D
#define KK 3584
#define QOFF 0
#define KOFF 29360128ULL        // B*NH*S*D
#define VOFF 33554432ULL        // KOFF + B*NKV*S*D

// GEMM tiling: 256x256 tile, BK=64, 8 waves (512 thr), 4 phases/K-tile
#define BM 256
#define BN 256
#define BK 64
#define NKT 56                  // KK/BK
#define NBN2 18                 // NN/BN
#define GRID_GEMM 576           // (MM/BM)*(NN/BN) = 32*18, 576%8==0 -> bijective XCD swizzle

// prep block ranges
#define NB_CVT 7168             // MM*KK/16/256
#define NB_TQ 3136              // (3584/64)*(3584/64)
#define NB_TK 448               // (512/64)*(3584/64)
#define NB_PREP (NB_CVT + NB_TQ + 2 * NB_TK)

typedef __bf16 bf16;
typedef bf16  bf16x8  __attribute__((ext_vector_type(8)));
typedef float floatx4 __attribute__((ext_vector_type(4)));

// ------------------------------------------------------------- fused prep ---
// blocks [0, NB_CVT):   A fp32 -> bf16 (16 floats / thread)
// blocks [NB_CVT, ...): W transpose+cvt into Bt, 64x64 tiles, bf16x8 stores
__global__ __launch_bounds__(256) void prep(
    const float* __restrict__ hs, const float* __restrict__ Wq,
    const float* __restrict__ Wk, const float* __restrict__ Wv,
    bf16* __restrict__ Abf, bf16* __restrict__ Bt) {

    int blk = blockIdx.x;
    if (blk < NB_CVT) {
        size_t i = (size_t)blk * 256 + threadIdx.x;      // 16 floats per thread
        const float4* s = (const float4*)hs;
        float4 a = s[4 * i], b = s[4 * i + 1], c = s[4 * i + 2], d = s[4 * i + 3];
        bf16x8 o0, o1;
        o0[0] = (bf16)a.x; o0[1] = (bf16)a.y; o0[2] = (bf16)a.z; o0[3] = (bf16)a.w;
        o0[4] = (bf16)b.x; o0[5] = (bf16)b.y; o0[6] = (bf16)b.z; o0[7] = (bf16)b.w;
        o1[0] = (bf16)c.x; o1[1] = (bf16)c.y; o1[2] = (bf16)c.z; o1[3] = (bf16)c.w;
        o1[4] = (bf16)d.x; o1[5] = (bf16)d.y; o1[6] = (bf16)d.z; o1[7] = (bf16)d.w;
        *(bf16x8*)(Abf + i * 16)     = o0;
        *(bf16x8*)(Abf + i * 16 + 8) = o1;
        return;
    }
    // ---- transpose part: 64x64 fp32 tile -> Bt (n,k) bf16 ----
    const float* W; int ncols, row_off, nb, kb;
    int t = blk - NB_CVT;
    if (t < NB_TQ)            { W = Wq; ncols = 3584; row_off = 0;    nb = t % 56; kb = t / 56; }
    else if (t < NB_TQ+NB_TK) { int u = t - NB_TQ;         W = Wk; ncols = 512; row_off = 3584; nb = u % 8; kb = u / 8; }
    else                      { int u = t - NB_TQ - NB_TK; W = Wv; ncols = 512; row_off = 4096; nb = u % 8; kb = u / 8; }

    __shared__ float tile[64][65];
    int n0 = nb * 64, k0 = kb * 64;
    int c4 = threadIdx.x & 15;          // float4 column
    int rr = threadIdx.x >> 4;          // 0..15
#pragma unroll
    for (int i = 0; i < 4; ++i) {
        int row = i * 16 + rr;
        float4 v = *(const float4*)(W + (size_t)(k0 + row) * ncols + n0 + c4 * 4);
        tile[row][c4 * 4 + 0] = v.x;
        tile[row][c4 * 4 + 1] = v.y;
        tile[row][c4 * 4 + 2] = v.z;
        tile[row][c4 * 4 + 3] = v.w;
    }
    __syncthreads();
    int kc  = threadIdx.x & 7;          // 16B k-chunk
    int nr0 = threadIdx.x >> 3;         // 0..31
#pragma unroll
    for (int cc = 0; cc < 2; ++cc) {
        int nrow = nr0 + cc * 32;
        bf16x8 o;
#pragma unroll
        for (int j = 0; j < 8; ++j) o[j] = (bf16)tile[kc * 8 + j][nrow];
        *(bf16x8*)(Bt + (size_t)(row_off + n0 + nrow) * KK + k0 + kc * 8) = o;
    }
}

// ----------------------------------------------------------------- GEMM -----
__device__ __forceinline__ void g2l16(const void* g, void* l) {
    __builtin_amdgcn_global_load_lds(
        (const __attribute__((address_space(1))) void*)g,
        (__attribute__((address_space(3))) void*)l, 16, 0, 0);
}

// Phase: ds-read frags (swizzled) | optional stage issue | barrier |
//        setprio(1) 16xMFMA setprio(0) | barrier.   H = mi-half, KX = k32 byte-xor.
#define PHASE(H, KX, STG) do {                                              \
    bf16x8 af[4], bfv[4];                                                   \
    _Pragma("unroll")                                                       \
    for (int mi = 0; mi < 4; ++mi)                                          \
        af[mi] = *(const bf16x8*)(lA + ((awb + ((H)*4 + mi) * 2048) ^ (KX)));\
    bfv[0] = *(const bf16x8*)(lB + ((bwb +     0) ^ (KX)));                 \
    bfv[1] = *(const bf16x8*)(lB + ((bwb +  8192) ^ (KX)));                 \
    bfv[2] = *(const bf16x8*)(lB + ((bwb +  2048) ^ (KX)));                 \
    bfv[3] = *(const bf16x8*)(lB + ((bwb + 10240) ^ (KX)));                 \
    STG;                                                                    \
    __builtin_amdgcn_s_barrier();                                           \
    __builtin_amdgcn_s_setprio(1);                                          \
    _Pragma("unroll")                                                       \
    for (int mi = 0; mi < 4; ++mi)                                          \
        _Pragma("unroll")                                                   \
        for (int ni = 0; ni < 4; ++ni)                                      \
            acc[(H)*4 + mi][ni] = __builtin_amdgcn_mfma_f32_16x16x32_bf16(  \
                af[mi], bfv[ni], acc[(H)*4 + mi][ni], 0, 0, 0);             \
    __builtin_amdgcn_s_setprio(0);                                          \
    __builtin_amdgcn_s_barrier();                                           \
  } while (0)

__global__ __launch_bounds__(512, 2) void qkv_gemm(
    const bf16* __restrict__ A, const bf16* __restrict__ Bt,
    const float* __restrict__ bq, const float* __restrict__ bk,
    const float* __restrict__ bv, const float* __restrict__ cosp,
    const float* __restrict__ sinp, float* __restrict__ out) {

    __shared__ __align__(16) bf16 As[2][BM * BK];   // 2 x 32 KB
    __shared__ __align__(16) bf16 Bs[2][BN * BK];   // 2 x 32 KB  (total 128 KB)

    const int tid  = threadIdx.x;
    const int lane = tid & 63;
    const int wave = tid >> 6;          // 0..7
    const int wm   = wave >> 2;         // M-half (rows wm*128..+127)
    const int wn   = wave & 3;
    const int hh   = wn >> 1;           // head within 256-col tile
    const int pw   = wn & 1;            // 32-col slice within head

    // bijective XCD swizzle (GRID_GEMM % 8 == 0)
    const int wg = (blockIdx.x & 7) * (GRID_GEMM / 8) + (blockIdx.x >> 3);
    const int bm = wg / NBN2;
    const int bn = wg % NBN2;
    const int m0 = bm * BM;
    const int n0 = bn * BN;

    // ---- staging: linear LDS dest (tid*16B), source k-chunk XOR-swizzled by row&7
    const int srow   = tid >> 3;                   // 0..63 (row within 64-row slab)
    const int schunk = (tid & 7) ^ (srow & 7);     // pre-swizzled global 16B chunk
    const bf16* aP = A  + (size_t)(m0 + srow) * KK + schunk * 8;
    const bf16* bP = Bt + (size_t)(n0 + srow) * KK + schunk * 8;

    auto STAGE_A = [&](int buf, int tt) {
        const bf16* a = aP + tt * BK;
        bf16* da = &As[buf][0] + tid * 8;
#pragma unroll
        for (int i = 0; i < 4; ++i)
            g2l16(a + (size_t)(i * 64) * KK, da + i * 4096);
    };
    auto STAGE_B = [&](int buf, int tt) {
        const bf16* b = bP + tt * BK;
        bf16* db = &Bs[buf][0] + tid * 8;
#pragma unroll
        for (int i = 0; i < 4; ++i)
            g2l16(b + (size_t)(i * 64) * KK, db + i * 4096);
    };

    // ---- fragment byte offsets (16x16x32: m/n = lane&15, k = (lane>>4)*8+j)
    // chunk stored at c' = c ^ (row&7); row bases are multiples of 16 so row&7==fr&7.
    // k32=1 <=> chunk^4 <=> byte^64.
    const int fr  = lane & 15;
    const int fq  = lane >> 4;
    const int fch = (fq ^ (fr & 7)) * 16;
    const int awb = (wm * 128 + fr) * 128 + fch;
    // RoPE-friendly cols: ni -> hh*128 + pw*32 + (ni>>1)*16 + (ni&1)*64
    // (byte deltas 0, 8192, 2048, 10240 hard-coded in PHASE)
    const int bwb = (hh * 128 + pw * 32 + fr) * 128 + fch;

    floatx4 acc[8][4];
#pragma unroll
    for (int mi = 0; mi < 8; ++mi)
#pragma unroll
        for (int ni = 0; ni < 4; ++ni)
            acc[mi][ni] = (floatx4){0.f, 0.f, 0.f, 0.f};

    // prologue: stage tile 0 into buf 0, drain, sync
    STAGE_A(0, 0);
    STAGE_B(0, 0);
    asm volatile("s_waitcnt vmcnt(0)" ::: "memory");
    __builtin_amdgcn_s_barrier();

    for (int t = 0; t < NKT; ++t) {
        const char* lA = (const char*)&As[t & 1][0];
        const char* lB = (const char*)&Bs[t & 1][0];
        const int  nbuf = (t & 1) ^ 1;
        const bool st   = (t + 1 < NKT);

        PHASE(0, 0,  if (st) { STAGE_A(nbuf, t + 1); });   // k32=0, rows 0..63
        PHASE(1, 0,  if (st) { STAGE_B(nbuf, t + 1); });   // k32=0, rows 64..127
        PHASE(0, 64, );                                    // k32=1
        PHASE(1, 64, );
        // single drain per K-tile: stage issued >=2 phases (~1200 cy) earlier
        asm volatile("s_waitcnt vmcnt(0)" ::: "memory");
        __builtin_amdgcn_s_barrier();
    }

    // ---- epilogue: bias + RoPE (register-local pairs) + permuted store -----
    const float* bias;
    int hbase, nh;
    size_t obase;
    bool rope;
    if (n0 < 3584)      { bias = bq + n0;          hbase = n0 >> 7;          obase = QOFF; nh = NHQ;  rope = true;  }
    else if (n0 < 4096) { bias = bk + (n0 - 3584); hbase = (n0 - 3584) >> 7; obase = KOFF; nh = NKVH; rope = true;  }
    else                { bias = bv + (n0 - 4096); hbase = (n0 - 4096) >> 7; obase = VOFF; nh = NKVH; rope = false; }
    const int h = hbase + hh;

    float blo[2], bhi[2];
#pragma unroll
    for (int p = 0; p < 2; ++p) {
        int d = pw * 32 + p * 16 + fr;     // in [0,64)
        blo[p] = bias[hh * 128 + d];
        bhi[p] = bias[hh * 128 + d + 64];
    }

#pragma unroll
    for (int mi = 0; mi < 8; ++mi) {
#pragma unroll
        for (int r = 0; r < 4; ++r) {
            int m = m0 + wm * 128 + mi * 16 + fq * 4 + r;   // C/D: row=quad*4+reg
            int b = m >> 12;                                // m / S
            int s = m & 4095;                               // m % S
            size_t orow = obase + ((size_t)(b * nh + h) * SS + s) * DD;
#pragma unroll
            for (int p = 0; p < 2; ++p) {
                int d = pw * 32 + p * 16 + fr;
                float xlo = acc[mi][2 * p][r] + blo[p];
                float xhi = acc[mi][2 * p + 1][r] + bhi[p];
                float ylo, yhi;
                if (rope) {
                    float c  = cosp[(size_t)m * DD + d];
                    float sn = sinp[(size_t)m * DD + d];
                    ylo = xlo * c - xhi * sn;      // d < 64:  x*cos - x_hi*sin
                    yhi = xhi * c + xlo * sn;      // d >= 64: x*cos + x_lo*sin
                } else {
                    ylo = xlo; yhi = xhi;
                }
                out[orow + d]      = ylo;
                out[orow + d + 64] = yhi;
            }
        }
    }
}

// ---------------------------------------------------------------- launch ----
extern "C" void kernel_launch(void* const* d_in, const int* in_sizes, int n_in,
                              void* d_out, int out_size, void* d_ws, size_t ws_size,
                              hipStream_t stream) {
    const float* hs   = (const float*)d_in[0];
    const float* cosp = (const float*)d_in[1];
    const float* sinp = (const float*)d_in[2];
    const float* Wq   = (const float*)d_in[3];
    const float* bq   = (const float*)d_in[4];
    const float* Wk   = (const float*)d_in[5];
    const float* bk   = (const float*)d_in[6];
    const float* Wv   = (const float*)d_in[7];
    const float* bv   = (const float*)d_in[8];
    float* out = (float*)d_out;

    bf16* Abf = (bf16*)d_ws;                      // 8192x3584 bf16 = 58.7 MB
    bf16* Btb = Abf + (size_t)MM * KK;            // 4608x3584 bf16 = 33.0 MB

    prep<<<NB_PREP, 256, 0, stream>>>(hs, Wq, Wk, Wv, Abf, Btb);
    qkv_gemm<<<GRID_GEMM, 512, 0, stream>>>(Abf, Btb, bq, bk, bv, cosp, sinp, out);
}